// Round 7
// baseline (4500.924 us; speedup 1.0000x reference)
//
#include <hip/hip_runtime.h>

// out[d] = sum_{e: dst[e]==d} x[src[e]]   (N=100k, E=1.6M, D=32 f32)
//
// r11-r15: sparse bucket-major bin + sort-gather = 111-113us.
// r16 dense bin: gather8 GOOD (~31us, -5us vs sparse) but scatter8 = 95us:
//   (a) 2046 same-address atomicAdds per cursor serialize (~46ns each);
//   (b) WRITE_SIZE 81MB vs 6.4MB payload -- bin lines receive 16 entries
//       from random XCDs -> dirty-line ping-pong across per-XCD L2s.
// r17: shard each bucket into 32 replicas = 8 XCD x 4 sub, replica picked
// from HW XCC_ID (s_getreg). Per-replica atomic chain 64 (not 2046); every
// bin segment + cursor row written by exactly ONE XCD -> L2-local write
// combining. Gather concatenates 32 segments (shfl-scan of 32 counts +
// gated quad copy), then identical count/rank/accumulate as gather8.
// Timing model: dur = fill(43, harness poison, fixed) + zero + scatter + gather.

#define D_FEAT 32
#define BKT_SHIFT 7
#define BKT_NODES 128
#define NREP 32               // 8 XCDs x 4 sub-replicas
#define RCAP 256              // slots per replica (mean 64; Poisson-safe)
#define RCAPSH 8
#define BKTSH 13              // NREP*RCAP = 8192 slots per bucket
#define OVFTOT 65536
// ---- legacy sparse-path params ----
#define CAPSH 4
#define CAP (1 << CAPSH)
#define ECAP 4096
#define OVFB 512
typedef unsigned int u32;

// ==================== dense-sharded path (r17) ====================

__global__ void __launch_bounds__(512)
k_zero8(u32* __restrict__ w, int nwords) {
    int t = threadIdx.x + blockIdx.x * 512;
    if (t < nwords) w[t] = 0u;
}

__global__ void __launch_bounds__(512)
k_scatter9(const int* __restrict__ src, const int* __restrict__ dst,
           u32* __restrict__ cursors, u32* __restrict__ bin,
           u32* __restrict__ ovfb, u32* __restrict__ ovfn,
           int n_edges, int nb) {
    int e = threadIdx.x + blockIdx.x * 512;
    if (e >= n_edges) return;
    u32 xcc;
    asm volatile("s_getreg_b32 %0, hwreg(HW_REG_XCC_ID)" : "=s"(xcc));
    u32 r = ((xcc & 7u) << 2) | ((u32)blockIdx.x & 3u);   // XCD-owned replica
    u32 d = (u32)dst[e];
    u32 b = d >> BKT_SHIFT;
    u32 packed = (u32)src[e] | ((d & (BKT_NODES - 1)) << 17);
    u32 pos = atomicAdd(&cursors[(size_t)r * nb + b], 1u);
    if (pos < (u32)RCAP) {
        bin[((size_t)b << BKTSH) + (r << RCAPSH) + pos] = packed;
    } else {
        u32 g = atomicAdd(ovfn, 1u);     // ~never taken
        if (g < (u32)OVFTOT) { ovfb[2 * g] = packed; ovfb[2 * g + 1] = b; }
    }
}

// One block per bucket: 32 replica counts -> shfl-scan -> gated segment
// concat into s_ent -> count by dlocal -> 128-scan -> rank -> register
// accumulate (4-way unrolled).
__global__ void __launch_bounds__(512)
k_gather9(const float* __restrict__ x, const u32* __restrict__ cursors,
          const u32* __restrict__ bin, const u32* __restrict__ ovfb,
          const u32* __restrict__ ovfn, float* __restrict__ out,
          int n_nodes, int nb) {
    __shared__ u32 s_rcnt[NREP];
    __shared__ u32 s_rbase[NREP + 1];
    __shared__ u32 s_ent[4096];
    __shared__ u32 s_srt[4096];
    __shared__ u32 s_off[BKT_NODES + 1];
    __shared__ u32 s_cur[BKT_NODES];
    int b = blockIdx.x, t = threadIdx.x;
    int lane = t & 63, wid = t >> 6;
    int node0 = b << BKT_SHIFT;
    const float4* x4 = (const float4*)x;
    int q = t & 7;
    int n0 = t >> 3;                       // nodes n0 and n0+64
    float4 a0 = make_float4(0.f, 0.f, 0.f, 0.f);
    float4 a1 = make_float4(0.f, 0.f, 0.f, 0.f);

    u32 ovct = min(*ovfn, (u32)OVFTOT);

    // replica counts + 32-wide exclusive scan in wave 0
    u32 c = 0u;
    if (t < NREP) {
        c = min(cursors[(size_t)t * nb + b], (u32)RCAP);
        s_rcnt[t] = c;
    }
    if (wid == 0) {
        u32 s = c;                         // lanes>=32 compute garbage, unused
        #pragma unroll
        for (int off = 1; off < NREP; off <<= 1) {
            u32 y = __shfl_up(s, off, 64);
            if (lane >= off) s += y;
        }
        if (lane < NREP) s_rbase[lane] = s - c;
        if (lane == NREP - 1) s_rbase[NREP] = s;
    }
    if (t < BKT_NODES) s_cur[t] = 0u;
    __syncthreads();
    u32 m = s_rbase[NREP];

    // gated segment concat: NREP segments of RCAP slots, cnt used each
    {
        const uint4* bin4 = (const uint4*)(bin + ((size_t)b << BKTSH));
        const int nquads = NREP * (RCAP / 4);            // 2048
        for (int i = t; i < nquads; i += 512) {
            int r   = i >> (RCAPSH - 2);
            int k4i = i & ((RCAP / 4) - 1);
            u32 cn = s_rcnt[r];
            u32 slot0 = (u32)(k4i << 2);
            if (slot0 < cn) {
                uint4 v = bin4[i];
                u32 base = s_rbase[r] + slot0;
                s_ent[base] = v.x;
                if (slot0 + 1 < cn) s_ent[base + 1] = v.y;
                if (slot0 + 2 < cn) s_ent[base + 2] = v.z;
                if (slot0 + 3 < cn) s_ent[base + 3] = v.w;
            }
        }
    }
    __syncthreads();

    // count by dlocal (entries are clean 24-bit: >>17 is dlocal)
    for (u32 i = t; i < m; i += 512) atomicAdd(&s_cur[s_ent[i] >> 17], 1u);
    __syncthreads();

    // 128-entry exclusive scan by wave 0 (2 entries/lane, shfl)
    if (wid == 0) {
        u32 v0 = s_cur[2 * lane], v1 = s_cur[2 * lane + 1];
        u32 ps = v0 + v1;
        #pragma unroll
        for (int off = 1; off < 64; off <<= 1) {
            u32 y = __shfl_up(ps, off, 64);
            if (lane >= off) ps += y;
        }
        u32 ex = ps - (v0 + v1);
        s_off[2 * lane] = ex;          s_cur[2 * lane] = ex;
        s_off[2 * lane + 1] = ex + v0; s_cur[2 * lane + 1] = ex + v0;
        if (lane == 63) s_off[BKT_NODES] = ps;
    }
    __syncthreads();

    // rank into s_srt
    for (u32 i = t; i < m; i += 512) {
        u32 p = s_ent[i];
        u32 pos = atomicAdd(&s_cur[p >> 17], 1u);
        s_srt[pos] = p & 0x1FFFFu;
    }
    __syncthreads();

    // accumulate: 8 lanes share one 128B x-row; 4-way unroll for MLP
    {
        u32 j = s_off[n0], j1 = s_off[n0 + 1];
        for (; j + 3 < j1; j += 4) {
            float4 xa = x4[(size_t)s_srt[j] * 8 + q];
            float4 xb = x4[(size_t)s_srt[j + 1] * 8 + q];
            float4 xc = x4[(size_t)s_srt[j + 2] * 8 + q];
            float4 xd = x4[(size_t)s_srt[j + 3] * 8 + q];
            a0.x += xa.x + xb.x + xc.x + xd.x;
            a0.y += xa.y + xb.y + xc.y + xd.y;
            a0.z += xa.z + xb.z + xc.z + xd.z;
            a0.w += xa.w + xb.w + xc.w + xd.w;
        }
        for (; j < j1; ++j) {
            float4 xa = x4[(size_t)s_srt[j] * 8 + q];
            a0.x += xa.x; a0.y += xa.y; a0.z += xa.z; a0.w += xa.w;
        }
        j = s_off[n0 + 64]; j1 = s_off[n0 + 65];
        for (; j + 3 < j1; j += 4) {
            float4 xa = x4[(size_t)s_srt[j] * 8 + q];
            float4 xb = x4[(size_t)s_srt[j + 1] * 8 + q];
            float4 xc = x4[(size_t)s_srt[j + 2] * 8 + q];
            float4 xd = x4[(size_t)s_srt[j + 3] * 8 + q];
            a1.x += xa.x + xb.x + xc.x + xd.x;
            a1.y += xa.y + xb.y + xc.y + xd.y;
            a1.z += xa.z + xb.z + xc.z + xd.z;
            a1.w += xa.w + xb.w + xc.w + xd.w;
        }
        for (; j < j1; ++j) {
            float4 xa = x4[(size_t)s_srt[j] * 8 + q];
            a1.x += xa.x; a1.y += xa.y; a1.z += xa.z; a1.w += xa.w;
        }
    }

    // replay global overflow list (normally empty)
    if (ovct) {
        for (u32 i = 0; i < ovct; ++i) {
            u32 ob = ovfb[2 * i + 1];
            if (ob == (u32)b) {
                u32 p = ovfb[2 * i];
                u32 dl = p >> 17;
                if (dl == (u32)n0 || dl == (u32)(n0 + 64)) {
                    float4 xv = x4[(size_t)(p & 0x1FFFFu) * 8 + q];
                    if (dl == (u32)n0) { a0.x += xv.x; a0.y += xv.y; a0.z += xv.z; a0.w += xv.w; }
                    else               { a1.x += xv.x; a1.y += xv.y; a1.z += xv.z; a1.w += xv.w; }
                }
            }
        }
    }

    float4* o4 = (float4*)out;
    if (node0 + n0 < n_nodes)      o4[(size_t)node0 * 8 + t] = a0;
    if (node0 + n0 + 64 < n_nodes) o4[(size_t)node0 * 8 + 512 + t] = a1;
}

// ==================== legacy sparse path (r15 proven, fallback) ============

__global__ void __launch_bounds__(512)
k_scatter6(const int* __restrict__ src, const int* __restrict__ dst,
           u32* __restrict__ bin, u32* __restrict__ ovfb, u32* __restrict__ ovfn,
           int n_edges, int nb, int nsub, int chunk) {
    extern __shared__ u32 smem[];
    u32* s_stage = smem;
    u32* s_cur   = smem + ((size_t)nb << CAPSH);
    __shared__ u32 s_ovf_n;
    int blk = blockIdx.x, t = threadIdx.x;
    for (int i = t; i < nb; i += 512) s_cur[i] = 0u;
    if (t == 0) s_ovf_n = 0u;
    __syncthreads();
    int beg = blk * chunk, end = min(beg + chunk, n_edges);
    for (int e = beg + t; e < end; e += 512) {
        u32 d = (u32)dst[e];
        u32 b = d >> BKT_SHIFT;
        u32 pos = atomicAdd(&s_cur[b], 1u);
        u32 packed = (u32)src[e] | ((d & (BKT_NODES - 1)) << 17);
        if (pos < (u32)CAP) {
            s_stage[(b << CAPSH) + pos] = packed;
        } else {
            u32 g = atomicAdd(&s_ovf_n, 1u);
            if (g < (u32)OVFB) {
                ovfb[((size_t)blk * OVFB + g) * 2]     = packed;
                ovfb[((size_t)blk * OVFB + g) * 2 + 1] = (u32)b;
            }
        }
    }
    __syncthreads();
    {
        const uint4* sq = (const uint4*)s_stage;
        uint4* gq = (uint4*)bin;
        int nquads = nb << (CAPSH - 2);
        for (int i = t; i < nquads; i += 512) {
            int b  = i >> (CAPSH - 2);
            int k4 = i & ((1 << (CAPSH - 2)) - 1);
            u32 cn = min(s_cur[b], (u32)CAP);
            size_t gidx = (((size_t)b * nsub + blk) << (CAPSH - 2)) + k4;
            if (k4 == 0) {
                uint4 v = sq[i];
                v.x = (v.x & 0x00FFFFFFu) | (cn << 24);
                gq[gidx] = v;
            } else if ((u32)(k4 << 2) < cn) {
                gq[gidx] = sq[i];
            }
        }
    }
    if (t == 0) ovfn[blk] = min(s_ovf_n, (u32)OVFB);
}

__global__ void __launch_bounds__(512)
k_gather7(const float* __restrict__ x, const u32* __restrict__ bin,
          const u32* __restrict__ ovfb, const u32* __restrict__ ovfn,
          float* __restrict__ out, int n_nodes, int nb, int nsub) {
    __shared__ u32 s_cnt[512];
    __shared__ u32 s_base[513];
    __shared__ u32 s_wsum[8];
    __shared__ u32 s_ent[ECAP];
    __shared__ u32 s_srt[ECAP];
    __shared__ u32 s_off[BKT_NODES + 1];
    __shared__ u32 s_cur[BKT_NODES];
    __shared__ u32 s_has;
    int b = blockIdx.x, t = threadIdx.x;
    int lane = t & 63, wid = t >> 6;
    int node0 = b * BKT_NODES;
    const float4* x4 = (const float4*)x;
    const uint4* bin4 = (const uint4*)bin;
    int q = t & 7;
    int n0 = t >> 3;
    float4 a0 = make_float4(0.f, 0.f, 0.f, 0.f);
    float4 a1 = make_float4(0.f, 0.f, 0.f, 0.f);

    u32 c = 0u;
    if (t < nsub) {
        u32 w = bin[((size_t)b * nsub + t) << CAPSH];
        c = (w >> 24) & 0x1Fu;
    }
    u32 myovf = (t < nsub) ? ovfn[t] : 0u;
    s_cnt[t] = c;
    if (t == 0) s_has = 0u;
    u32 s = c;
    #pragma unroll
    for (int off = 1; off < 64; off <<= 1) {
        u32 y = __shfl_up(s, off, 64);
        if (lane >= off) s += y;
    }
    if (lane == 63) s_wsum[wid] = s;
    __syncthreads();
    if (t == 0) {
        u32 run = 0u;
        #pragma unroll
        for (int w = 0; w < 8; ++w) { u32 v = s_wsum[w]; s_wsum[w] = run; run += v; }
    }
    if (myovf) atomicOr(&s_has, 1u);
    __syncthreads();
    u32 incl = s + s_wsum[wid];
    s_base[t] = incl - c;
    if (t == 511) s_base[512] = incl;
    __syncthreads();

    int subA = 0;
    u32 baseA = 0u;
    while (subA < nsub) {
        int lo = subA + 1, hi = nsub;
        while (lo < hi) {
            int mid = (lo + hi + 1) >> 1;
            if (s_base[mid] - baseA <= (u32)ECAP) lo = mid; else hi = mid - 1;
        }
        int subB = lo;
        int m = (int)(s_base[subB] - baseA);

        {
            int quads = (subB - subA) << (CAPSH - 2);
            size_t qbase = ((size_t)b * nsub + subA) << (CAPSH - 2);
            for (int i = t; i < quads; i += 512) {
                int sub = subA + (i >> (CAPSH - 2));
                int slot0 = (i & ((1 << (CAPSH - 2)) - 1)) << 2;
                u32 cn = s_cnt[sub];
                if ((u32)slot0 < cn) {
                    uint4 v = bin4[qbase + i];
                    u32 base = (s_base[sub] - baseA) + slot0;
                    s_ent[base] = v.x;
                    if ((u32)(slot0 + 1) < cn) s_ent[base + 1] = v.y;
                    if ((u32)(slot0 + 2) < cn) s_ent[base + 2] = v.z;
                    if ((u32)(slot0 + 3) < cn) s_ent[base + 3] = v.w;
                }
            }
        }
        if (t < BKT_NODES) s_cur[t] = 0u;
        __syncthreads();

        for (int i = t; i < m; i += 512) atomicAdd(&s_cur[(s_ent[i] >> 17) & 127u], 1u);
        __syncthreads();

        if (wid == 0) {
            u32 v0 = s_cur[2 * lane], v1 = s_cur[2 * lane + 1];
            u32 ps = v0 + v1;
            #pragma unroll
            for (int off = 1; off < 64; off <<= 1) {
                u32 y = __shfl_up(ps, off, 64);
                if (lane >= off) ps += y;
            }
            u32 ex = ps - (v0 + v1);
            s_off[2 * lane] = ex;     s_cur[2 * lane] = ex;
            s_off[2 * lane + 1] = ex + v0; s_cur[2 * lane + 1] = ex + v0;
            if (lane == 63) s_off[BKT_NODES] = ps;
        }
        __syncthreads();

        for (int i = t; i < m; i += 512) {
            u32 p = s_ent[i];
            u32 pos = atomicAdd(&s_cur[(p >> 17) & 127u], 1u);
            s_srt[pos] = p & 0x1FFFFu;
        }
        __syncthreads();

        {
            u32 j = s_off[n0], j1 = s_off[n0 + 1];
            for (; j + 3 < j1; j += 4) {
                float4 xa = x4[(size_t)s_srt[j] * 8 + q];
                float4 xb = x4[(size_t)s_srt[j + 1] * 8 + q];
                float4 xc = x4[(size_t)s_srt[j + 2] * 8 + q];
                float4 xd = x4[(size_t)s_srt[j + 3] * 8 + q];
                a0.x += xa.x + xb.x + xc.x + xd.x;
                a0.y += xa.y + xb.y + xc.y + xd.y;
                a0.z += xa.z + xb.z + xc.z + xd.z;
                a0.w += xa.w + xb.w + xc.w + xd.w;
            }
            for (; j < j1; ++j) {
                float4 xa = x4[(size_t)s_srt[j] * 8 + q];
                a0.x += xa.x; a0.y += xa.y; a0.z += xa.z; a0.w += xa.w;
            }
            j = s_off[n0 + 64]; j1 = s_off[n0 + 65];
            for (; j + 3 < j1; j += 4) {
                float4 xa = x4[(size_t)s_srt[j] * 8 + q];
                float4 xb = x4[(size_t)s_srt[j + 1] * 8 + q];
                float4 xc = x4[(size_t)s_srt[j + 2] * 8 + q];
                float4 xd = x4[(size_t)s_srt[j + 3] * 8 + q];
                a1.x += xa.x + xb.x + xc.x + xd.x;
                a1.y += xa.y + xb.y + xc.y + xd.y;
                a1.z += xa.z + xb.z + xc.z + xd.z;
                a1.w += xa.w + xb.w + xc.w + xd.w;
            }
            for (; j < j1; ++j) {
                float4 xa = x4[(size_t)s_srt[j] * 8 + q];
                a1.x += xa.x; a1.y += xa.y; a1.z += xa.z; a1.w += xa.w;
            }
        }
        __syncthreads();
        subA = subB;
        baseA = s_base[subB];
    }

    if (s_has) {
        for (int sub = 0; sub < nsub; ++sub) {
            u32 n = ovfn[sub];
            for (u32 i = 0; i < n; ++i) {
                u32 ob = ovfb[((size_t)sub * OVFB + i) * 2 + 1];
                if (ob == (u32)b) {
                    u32 p = ovfb[((size_t)sub * OVFB + i) * 2];
                    u32 dl = (p >> 17) & 127u;
                    if (dl == (u32)n0 || dl == (u32)(n0 + 64)) {
                        float4 xv = x4[(size_t)(p & 0x1FFFFu) * 8 + q];
                        if (dl == (u32)n0) { a0.x += xv.x; a0.y += xv.y; a0.z += xv.z; a0.w += xv.w; }
                        else               { a1.x += xv.x; a1.y += xv.y; a1.z += xv.z; a1.w += xv.w; }
                    }
                }
            }
        }
    }

    float4* o4 = (float4*)out;
    if (node0 + n0 < n_nodes)      o4[(size_t)node0 * 8 + t] = a0;
    if (node0 + n0 + 64 < n_nodes) o4[(size_t)node0 * 8 + 512 + t] = a1;
}

// ---------------- last-resort atomic path ----------------

__global__ void __launch_bounds__(256)
mp_zero_kernel(float* __restrict__ out, int n) {
    int i = blockIdx.x * blockDim.x + threadIdx.x;
    if (i < n) out[i] = 0.0f;
}

__global__ void __launch_bounds__(256)
mp_scatter_kernel(const float* __restrict__ x, const int* __restrict__ src,
                  const int* __restrict__ dst, float* __restrict__ out,
                  int n_edges) {
    int idx = blockIdx.x * blockDim.x + threadIdx.x;
    if (idx >= n_edges * 8) return;
    int e = idx >> 3;
    int c = idx & 7;
    const float4 v = *reinterpret_cast<const float4*>(x + (size_t)src[e] * D_FEAT + c * 4);
    float* o = out + (size_t)dst[e] * D_FEAT + c * 4;
    unsafeAtomicAdd(o + 0, v.x);
    unsafeAtomicAdd(o + 1, v.y);
    unsafeAtomicAdd(o + 2, v.z);
    unsafeAtomicAdd(o + 3, v.w);
}

// ==================== launch ====================

extern "C" void kernel_launch(void* const* d_in, const int* in_sizes, int n_in,
                              void* d_out, int out_size, void* d_ws, size_t ws_size,
                              hipStream_t stream) {
    const float* x = (const float*)d_in[0];
    const int* edge_index = (const int*)d_in[1];
    int n_edges = in_sizes[1] / 2;
    const int* src = edge_index;            // row 0: source j
    const int* dst = edge_index + n_edges;  // row 1: target i
    float* out = (float*)d_out;
    int n_nodes = out_size / D_FEAT;

    int nb = (n_nodes + BKT_NODES - 1) >> BKT_SHIFT;     // 782

    // ---- preferred: XCD-sharded dense bin, 3-dispatch path ----
    {
        // layout: bin[nb<<BKTSH] | cursors[NREP*nb] | ovfn[1] | ovfb[2*OVFTOT]
        size_t w_bin = (size_t)nb << BKTSH;              // 25.6MB @ nb=782
        size_t w_cur = (size_t)NREP * nb;
        size_t need = (w_bin + w_cur + 1 + 2 * (size_t)OVFTOT) * sizeof(u32);
        if (n_nodes <= (1 << 17) && need <= ws_size) {
            u32* bin     = (u32*)d_ws;
            u32* cursors = bin + w_bin;
            u32* ovfn    = cursors + w_cur;
            u32* ovfb    = ovfn + 1;
            int zero_words = (int)(w_cur + 1);           // cursors + ovfn
            k_zero8<<<(zero_words + 511) / 512, 512, 0, stream>>>(cursors, zero_words);
            k_scatter9<<<(n_edges + 511) / 512, 512, 0, stream>>>(src, dst, cursors, bin,
                                                                  ovfb, ovfn, n_edges, nb);
            k_gather9<<<nb, 512, 0, stream>>>(x, cursors, bin, ovfb, ovfn, out,
                                              n_nodes, nb);
            return;
        }
    }

    // ---- fallback: proven sparse 2-kernel path ----
    size_t sc_lds = ((size_t)nb * CAP + nb) * sizeof(u32);   // 53.2 KB @ nb=782
    if (n_nodes <= (1 << 17) && sc_lds <= 64 * 1024) {
        const int ncand[3] = {512, 384, 256};
        for (int ci = 0; ci < 3; ++ci) {
            int nsub = ncand[ci];
            int chunk = (n_edges + nsub - 1) / nsub;
            size_t need = (512
                           + 2 * (size_t)nsub * OVFB
                           + (((size_t)nb * nsub) << CAPSH))
                          * sizeof(u32);
            if (need > ws_size) continue;

            u32* ovfn = (u32*)d_ws;
            u32* ovfb = ovfn + 512;
            u32* bin  = ovfb + 2 * (size_t)nsub * OVFB;

            k_scatter6<<<nsub, 512, sc_lds, stream>>>(src, dst, bin, ovfb, ovfn,
                                                      n_edges, nb, nsub, chunk);
            k_gather7<<<nb, 512, 0, stream>>>(x, bin, ovfb, ovfn, out,
                                              n_nodes, nb, nsub);
            return;
        }
    }

    // last-resort: atomic path
    mp_zero_kernel<<<(out_size + 255) / 256, 256, 0, stream>>>(out, out_size);
    int total_thr = n_edges * 8;
    mp_scatter_kernel<<<(total_thr + 255) / 256, 256, 0, stream>>>(x, src, dst, out, n_edges);
}

// Round 8
// 156.775 us; speedup vs baseline: 28.7095x; 28.7095x over previous
//
#include <hip/hip_runtime.h>

// out[d] = sum_{e: dst[e]==d} x[src[e]]   (N=100k, E=1.6M, D=32 f32)
//
// r11-r15: sparse bucket-major bin + sort-gather = 111-113us.
// r16 dense bin: gather8 GOOD (~31us) but scatter8 95us (2046-deep cursor
//   atomic chains + cross-XCD bin-line ping-pong, WRITE 81MB).
// r17 XCD-sharded replicas FAILED 4.5ms: (blockIdx&3) is CORRELATED with
//   XCC_ID under round-robin dispatch -> only 8/32 replicas used -> mean
//   fill 256 = RCAP -> ~40K overflows -> every block serially scanned the
//   overflow list (4.25ms in gather9).
// r18: (1) decorrelated sub-replica r = (xcc&7)<<2 | (blockIdx>>3)&3 --
//   all 32 replicas, mean 64/cell, 24-sigma headroom; (2) overflow replay
//   moved OUT of gather into a tiny post-kernel (atomicAdd on out, after
//   gather's overwrite) -- gather can never hit the serial-scan path again.
// Timing model: dur = fill(43, harness poison) + zero + scatter + gather + ovf.

#define D_FEAT 32
#define BKT_SHIFT 7
#define BKT_NODES 128
#define NREP 32               // 8 XCDs x 4 sub-replicas
#define RCAP 256              // slots per replica (mean 64; 24-sigma safe)
#define RCAPSH 8
#define BKTSH 13              // NREP*RCAP = 8192 slots per bucket
#define OVFTOT 32768
// ---- legacy sparse-path params ----
#define CAPSH 4
#define CAP (1 << CAPSH)
#define ECAP 4096
#define OVFB 512
typedef unsigned int u32;

// ==================== dense-sharded path (r18) ====================

__global__ void __launch_bounds__(512)
k_zero8(u32* __restrict__ w, int nwords) {
    int t = threadIdx.x + blockIdx.x * 512;
    if (t < nwords) w[t] = 0u;
}

__global__ void __launch_bounds__(512)
k_scatter9(const int* __restrict__ src, const int* __restrict__ dst,
           u32* __restrict__ cursors, u32* __restrict__ bin,
           u32* __restrict__ ovfb, u32* __restrict__ ovfn,
           int n_edges, int nb) {
    int e = threadIdx.x + blockIdx.x * 512;
    if (e >= n_edges) return;
    u32 xcc;
    asm volatile("s_getreg_b32 %0, hwreg(HW_REG_XCC_ID)" : "=s"(xcc));
    // sub-replica from blockIdx>>3: INDEPENDENT of XCD under round-robin
    // dispatch (blockIdx&7 determines XCD; r17's &3 was correlated).
    u32 r = ((xcc & 7u) << 2) | (((u32)blockIdx.x >> 3) & 3u);
    u32 d = (u32)dst[e];
    u32 b = d >> BKT_SHIFT;
    u32 packed = (u32)src[e] | ((d & (BKT_NODES - 1)) << 17);
    u32 pos = atomicAdd(&cursors[(size_t)r * nb + b], 1u);
    if (pos < (u32)RCAP) {
        bin[((size_t)b << BKTSH) + (r << RCAPSH) + pos] = packed;
    } else {
        u32 g = atomicAdd(ovfn, 1u);     // ~never taken (24 sigma)
        if (g < (u32)OVFTOT) { ovfb[2 * g] = packed; ovfb[2 * g + 1] = b; }
    }
}

// One block per bucket: 32 replica counts -> shfl-scan -> gated segment
// concat into s_ent -> count by dlocal -> 128-scan -> rank -> register
// accumulate (4-way unrolled). NO overflow handling here (post-kernel).
__global__ void __launch_bounds__(512)
k_gather9(const float* __restrict__ x, const u32* __restrict__ cursors,
          const u32* __restrict__ bin, float* __restrict__ out,
          int n_nodes, int nb) {
    __shared__ u32 s_rcnt[NREP];
    __shared__ u32 s_rbase[NREP + 1];
    __shared__ u32 s_ent[4096];
    __shared__ u32 s_srt[4096];
    __shared__ u32 s_off[BKT_NODES + 1];
    __shared__ u32 s_cur[BKT_NODES];
    int b = blockIdx.x, t = threadIdx.x;
    int lane = t & 63, wid = t >> 6;
    int node0 = b << BKT_SHIFT;
    const float4* x4 = (const float4*)x;
    int q = t & 7;
    int n0 = t >> 3;                       // nodes n0 and n0+64
    float4 a0 = make_float4(0.f, 0.f, 0.f, 0.f);
    float4 a1 = make_float4(0.f, 0.f, 0.f, 0.f);

    // replica counts + 32-wide exclusive scan in wave 0
    u32 c = 0u;
    if (t < NREP) {
        c = min(cursors[(size_t)t * nb + b], (u32)RCAP);
        s_rcnt[t] = c;
    }
    if (wid == 0) {
        u32 s = c;                         // lanes>=32 compute garbage, unused
        #pragma unroll
        for (int off = 1; off < NREP; off <<= 1) {
            u32 y = __shfl_up(s, off, 64);
            if (lane >= off) s += y;
        }
        if (lane < NREP) s_rbase[lane] = s - c;
        if (lane == NREP - 1) s_rbase[NREP] = s;
    }
    if (t < BKT_NODES) s_cur[t] = 0u;
    __syncthreads();
    u32 m = s_rbase[NREP];

    // gated segment concat: NREP segments of RCAP slots, cnt used each
    {
        const uint4* bin4 = (const uint4*)(bin + ((size_t)b << BKTSH));
        const int nquads = NREP * (RCAP / 4);            // 2048
        for (int i = t; i < nquads; i += 512) {
            int r   = i >> (RCAPSH - 2);
            int k4i = i & ((RCAP / 4) - 1);
            u32 cn = s_rcnt[r];
            u32 slot0 = (u32)(k4i << 2);
            if (slot0 < cn) {
                uint4 v = bin4[i];
                u32 base = s_rbase[r] + slot0;
                s_ent[base] = v.x;
                if (slot0 + 1 < cn) s_ent[base + 1] = v.y;
                if (slot0 + 2 < cn) s_ent[base + 2] = v.z;
                if (slot0 + 3 < cn) s_ent[base + 3] = v.w;
            }
        }
    }
    __syncthreads();

    // count by dlocal (entries are clean 24-bit: >>17 is dlocal)
    for (u32 i = t; i < m; i += 512) atomicAdd(&s_cur[s_ent[i] >> 17], 1u);
    __syncthreads();

    // 128-entry exclusive scan by wave 0 (2 entries/lane, shfl)
    if (wid == 0) {
        u32 v0 = s_cur[2 * lane], v1 = s_cur[2 * lane + 1];
        u32 ps = v0 + v1;
        #pragma unroll
        for (int off = 1; off < 64; off <<= 1) {
            u32 y = __shfl_up(ps, off, 64);
            if (lane >= off) ps += y;
        }
        u32 ex = ps - (v0 + v1);
        s_off[2 * lane] = ex;          s_cur[2 * lane] = ex;
        s_off[2 * lane + 1] = ex + v0; s_cur[2 * lane + 1] = ex + v0;
        if (lane == 63) s_off[BKT_NODES] = ps;
    }
    __syncthreads();

    // rank into s_srt
    for (u32 i = t; i < m; i += 512) {
        u32 p = s_ent[i];
        u32 pos = atomicAdd(&s_cur[p >> 17], 1u);
        s_srt[pos] = p & 0x1FFFFu;
    }
    __syncthreads();

    // accumulate: 8 lanes share one 128B x-row; 4-way unroll for MLP
    {
        u32 j = s_off[n0], j1 = s_off[n0 + 1];
        for (; j + 3 < j1; j += 4) {
            float4 xa = x4[(size_t)s_srt[j] * 8 + q];
            float4 xb = x4[(size_t)s_srt[j + 1] * 8 + q];
            float4 xc = x4[(size_t)s_srt[j + 2] * 8 + q];
            float4 xd = x4[(size_t)s_srt[j + 3] * 8 + q];
            a0.x += xa.x + xb.x + xc.x + xd.x;
            a0.y += xa.y + xb.y + xc.y + xd.y;
            a0.z += xa.z + xb.z + xc.z + xd.z;
            a0.w += xa.w + xb.w + xc.w + xd.w;
        }
        for (; j < j1; ++j) {
            float4 xa = x4[(size_t)s_srt[j] * 8 + q];
            a0.x += xa.x; a0.y += xa.y; a0.z += xa.z; a0.w += xa.w;
        }
        j = s_off[n0 + 64]; j1 = s_off[n0 + 65];
        for (; j + 3 < j1; j += 4) {
            float4 xa = x4[(size_t)s_srt[j] * 8 + q];
            float4 xb = x4[(size_t)s_srt[j + 1] * 8 + q];
            float4 xc = x4[(size_t)s_srt[j + 2] * 8 + q];
            float4 xd = x4[(size_t)s_srt[j + 3] * 8 + q];
            a1.x += xa.x + xb.x + xc.x + xd.x;
            a1.y += xa.y + xb.y + xc.y + xd.y;
            a1.z += xa.z + xb.z + xc.z + xd.z;
            a1.w += xa.w + xb.w + xc.w + xd.w;
        }
        for (; j < j1; ++j) {
            float4 xa = x4[(size_t)s_srt[j] * 8 + q];
            a1.x += xa.x; a1.y += xa.y; a1.z += xa.z; a1.w += xa.w;
        }
    }

    float4* o4 = (float4*)out;
    if (node0 + n0 < n_nodes)      o4[(size_t)node0 * 8 + t] = a0;
    if (node0 + n0 + 64 < n_nodes) o4[(size_t)node0 * 8 + 512 + t] = a1;
}

// post-gather overflow replay: one thread per (entry, float4-col).
// Runs after gather's full overwrite of out; normally all-empty early exit.
__global__ void __launch_bounds__(256)
k_ovf(const float* __restrict__ x, const u32* __restrict__ ovfb,
      const u32* __restrict__ ovfn, float* __restrict__ out, int n_nodes) {
    u32 n = min(*ovfn, (u32)OVFTOT);
    u32 idx = threadIdx.x + blockIdx.x * 256;
    if (idx >= n * 8u) return;
    u32 i = idx >> 3, c = idx & 7u;
    u32 p = ovfb[2 * i];
    u32 b = ovfb[2 * i + 1];
    u32 node = (b << BKT_SHIFT) + (p >> 17);
    if (node < (u32)n_nodes) {
        const float4 v = ((const float4*)x)[(size_t)(p & 0x1FFFFu) * 8 + c];
        float* o = out + (size_t)node * D_FEAT + c * 4;
        unsafeAtomicAdd(o + 0, v.x);
        unsafeAtomicAdd(o + 1, v.y);
        unsafeAtomicAdd(o + 2, v.z);
        unsafeAtomicAdd(o + 3, v.w);
    }
}

// ==================== legacy sparse path (r15 proven, fallback) ============

__global__ void __launch_bounds__(512)
k_scatter6(const int* __restrict__ src, const int* __restrict__ dst,
           u32* __restrict__ bin, u32* __restrict__ ovfb, u32* __restrict__ ovfn,
           int n_edges, int nb, int nsub, int chunk) {
    extern __shared__ u32 smem[];
    u32* s_stage = smem;
    u32* s_cur   = smem + ((size_t)nb << CAPSH);
    __shared__ u32 s_ovf_n;
    int blk = blockIdx.x, t = threadIdx.x;
    for (int i = t; i < nb; i += 512) s_cur[i] = 0u;
    if (t == 0) s_ovf_n = 0u;
    __syncthreads();
    int beg = blk * chunk, end = min(beg + chunk, n_edges);
    for (int e = beg + t; e < end; e += 512) {
        u32 d = (u32)dst[e];
        u32 b = d >> BKT_SHIFT;
        u32 pos = atomicAdd(&s_cur[b], 1u);
        u32 packed = (u32)src[e] | ((d & (BKT_NODES - 1)) << 17);
        if (pos < (u32)CAP) {
            s_stage[(b << CAPSH) + pos] = packed;
        } else {
            u32 g = atomicAdd(&s_ovf_n, 1u);
            if (g < (u32)OVFB) {
                ovfb[((size_t)blk * OVFB + g) * 2]     = packed;
                ovfb[((size_t)blk * OVFB + g) * 2 + 1] = (u32)b;
            }
        }
    }
    __syncthreads();
    {
        const uint4* sq = (const uint4*)s_stage;
        uint4* gq = (uint4*)bin;
        int nquads = nb << (CAPSH - 2);
        for (int i = t; i < nquads; i += 512) {
            int b  = i >> (CAPSH - 2);
            int k4 = i & ((1 << (CAPSH - 2)) - 1);
            u32 cn = min(s_cur[b], (u32)CAP);
            size_t gidx = (((size_t)b * nsub + blk) << (CAPSH - 2)) + k4;
            if (k4 == 0) {
                uint4 v = sq[i];
                v.x = (v.x & 0x00FFFFFFu) | (cn << 24);
                gq[gidx] = v;
            } else if ((u32)(k4 << 2) < cn) {
                gq[gidx] = sq[i];
            }
        }
    }
    if (t == 0) ovfn[blk] = min(s_ovf_n, (u32)OVFB);
}

__global__ void __launch_bounds__(512)
k_gather7(const float* __restrict__ x, const u32* __restrict__ bin,
          const u32* __restrict__ ovfb, const u32* __restrict__ ovfn,
          float* __restrict__ out, int n_nodes, int nb, int nsub) {
    __shared__ u32 s_cnt[512];
    __shared__ u32 s_base[513];
    __shared__ u32 s_wsum[8];
    __shared__ u32 s_ent[ECAP];
    __shared__ u32 s_srt[ECAP];
    __shared__ u32 s_off[BKT_NODES + 1];
    __shared__ u32 s_cur[BKT_NODES];
    __shared__ u32 s_has;
    int b = blockIdx.x, t = threadIdx.x;
    int lane = t & 63, wid = t >> 6;
    int node0 = b * BKT_NODES;
    const float4* x4 = (const float4*)x;
    const uint4* bin4 = (const uint4*)bin;
    int q = t & 7;
    int n0 = t >> 3;
    float4 a0 = make_float4(0.f, 0.f, 0.f, 0.f);
    float4 a1 = make_float4(0.f, 0.f, 0.f, 0.f);

    u32 c = 0u;
    if (t < nsub) {
        u32 w = bin[((size_t)b * nsub + t) << CAPSH];
        c = (w >> 24) & 0x1Fu;
    }
    u32 myovf = (t < nsub) ? ovfn[t] : 0u;
    s_cnt[t] = c;
    if (t == 0) s_has = 0u;
    u32 s = c;
    #pragma unroll
    for (int off = 1; off < 64; off <<= 1) {
        u32 y = __shfl_up(s, off, 64);
        if (lane >= off) s += y;
    }
    if (lane == 63) s_wsum[wid] = s;
    __syncthreads();
    if (t == 0) {
        u32 run = 0u;
        #pragma unroll
        for (int w = 0; w < 8; ++w) { u32 v = s_wsum[w]; s_wsum[w] = run; run += v; }
    }
    if (myovf) atomicOr(&s_has, 1u);
    __syncthreads();
    u32 incl = s + s_wsum[wid];
    s_base[t] = incl - c;
    if (t == 511) s_base[512] = incl;
    __syncthreads();

    int subA = 0;
    u32 baseA = 0u;
    while (subA < nsub) {
        int lo = subA + 1, hi = nsub;
        while (lo < hi) {
            int mid = (lo + hi + 1) >> 1;
            if (s_base[mid] - baseA <= (u32)ECAP) lo = mid; else hi = mid - 1;
        }
        int subB = lo;
        int m = (int)(s_base[subB] - baseA);

        {
            int quads = (subB - subA) << (CAPSH - 2);
            size_t qbase = ((size_t)b * nsub + subA) << (CAPSH - 2);
            for (int i = t; i < quads; i += 512) {
                int sub = subA + (i >> (CAPSH - 2));
                int slot0 = (i & ((1 << (CAPSH - 2)) - 1)) << 2;
                u32 cn = s_cnt[sub];
                if ((u32)slot0 < cn) {
                    uint4 v = bin4[qbase + i];
                    u32 base = (s_base[sub] - baseA) + slot0;
                    s_ent[base] = v.x;
                    if ((u32)(slot0 + 1) < cn) s_ent[base + 1] = v.y;
                    if ((u32)(slot0 + 2) < cn) s_ent[base + 2] = v.z;
                    if ((u32)(slot0 + 3) < cn) s_ent[base + 3] = v.w;
                }
            }
        }
        if (t < BKT_NODES) s_cur[t] = 0u;
        __syncthreads();

        for (int i = t; i < m; i += 512) atomicAdd(&s_cur[(s_ent[i] >> 17) & 127u], 1u);
        __syncthreads();

        if (wid == 0) {
            u32 v0 = s_cur[2 * lane], v1 = s_cur[2 * lane + 1];
            u32 ps = v0 + v1;
            #pragma unroll
            for (int off = 1; off < 64; off <<= 1) {
                u32 y = __shfl_up(ps, off, 64);
                if (lane >= off) ps += y;
            }
            u32 ex = ps - (v0 + v1);
            s_off[2 * lane] = ex;     s_cur[2 * lane] = ex;
            s_off[2 * lane + 1] = ex + v0; s_cur[2 * lane + 1] = ex + v0;
            if (lane == 63) s_off[BKT_NODES] = ps;
        }
        __syncthreads();

        for (int i = t; i < m; i += 512) {
            u32 p = s_ent[i];
            u32 pos = atomicAdd(&s_cur[(p >> 17) & 127u], 1u);
            s_srt[pos] = p & 0x1FFFFu;
        }
        __syncthreads();

        {
            u32 j = s_off[n0], j1 = s_off[n0 + 1];
            for (; j + 3 < j1; j += 4) {
                float4 xa = x4[(size_t)s_srt[j] * 8 + q];
                float4 xb = x4[(size_t)s_srt[j + 1] * 8 + q];
                float4 xc = x4[(size_t)s_srt[j + 2] * 8 + q];
                float4 xd = x4[(size_t)s_srt[j + 3] * 8 + q];
                a0.x += xa.x + xb.x + xc.x + xd.x;
                a0.y += xa.y + xb.y + xc.y + xd.y;
                a0.z += xa.z + xb.z + xc.z + xd.z;
                a0.w += xa.w + xb.w + xc.w + xd.w;
            }
            for (; j < j1; ++j) {
                float4 xa = x4[(size_t)s_srt[j] * 8 + q];
                a0.x += xa.x; a0.y += xa.y; a0.z += xa.z; a0.w += xa.w;
            }
            j = s_off[n0 + 64]; j1 = s_off[n0 + 65];
            for (; j + 3 < j1; j += 4) {
                float4 xa = x4[(size_t)s_srt[j] * 8 + q];
                float4 xb = x4[(size_t)s_srt[j + 1] * 8 + q];
                float4 xc = x4[(size_t)s_srt[j + 2] * 8 + q];
                float4 xd = x4[(size_t)s_srt[j + 3] * 8 + q];
                a1.x += xa.x + xb.x + xc.x + xd.x;
                a1.y += xa.y + xb.y + xc.y + xd.y;
                a1.z += xa.z + xb.z + xc.z + xd.z;
                a1.w += xa.w + xb.w + xc.w + xd.w;
            }
            for (; j < j1; ++j) {
                float4 xa = x4[(size_t)s_srt[j] * 8 + q];
                a1.x += xa.x; a1.y += xa.y; a1.z += xa.z; a1.w += xa.w;
            }
        }
        __syncthreads();
        subA = subB;
        baseA = s_base[subB];
    }

    if (s_has) {
        for (int sub = 0; sub < nsub; ++sub) {
            u32 n = ovfn[sub];
            for (u32 i = 0; i < n; ++i) {
                u32 ob = ovfb[((size_t)sub * OVFB + i) * 2 + 1];
                if (ob == (u32)b) {
                    u32 p = ovfb[((size_t)sub * OVFB + i) * 2];
                    u32 dl = (p >> 17) & 127u;
                    if (dl == (u32)n0 || dl == (u32)(n0 + 64)) {
                        float4 xv = x4[(size_t)(p & 0x1FFFFu) * 8 + q];
                        if (dl == (u32)n0) { a0.x += xv.x; a0.y += xv.y; a0.z += xv.z; a0.w += xv.w; }
                        else               { a1.x += xv.x; a1.y += xv.y; a1.z += xv.z; a1.w += xv.w; }
                    }
                }
            }
        }
    }

    float4* o4 = (float4*)out;
    if (node0 + n0 < n_nodes)      o4[(size_t)node0 * 8 + t] = a0;
    if (node0 + n0 + 64 < n_nodes) o4[(size_t)node0 * 8 + 512 + t] = a1;
}

// ---------------- last-resort atomic path ----------------

__global__ void __launch_bounds__(256)
mp_zero_kernel(float* __restrict__ out, int n) {
    int i = blockIdx.x * blockDim.x + threadIdx.x;
    if (i < n) out[i] = 0.0f;
}

__global__ void __launch_bounds__(256)
mp_scatter_kernel(const float* __restrict__ x, const int* __restrict__ src,
                  const int* __restrict__ dst, float* __restrict__ out,
                  int n_edges) {
    int idx = blockIdx.x * blockDim.x + threadIdx.x;
    if (idx >= n_edges * 8) return;
    int e = idx >> 3;
    int c = idx & 7;
    const float4 v = *reinterpret_cast<const float4*>(x + (size_t)src[e] * D_FEAT + c * 4);
    float* o = out + (size_t)dst[e] * D_FEAT + c * 4;
    unsafeAtomicAdd(o + 0, v.x);
    unsafeAtomicAdd(o + 1, v.y);
    unsafeAtomicAdd(o + 2, v.z);
    unsafeAtomicAdd(o + 3, v.w);
}

// ==================== launch ====================

extern "C" void kernel_launch(void* const* d_in, const int* in_sizes, int n_in,
                              void* d_out, int out_size, void* d_ws, size_t ws_size,
                              hipStream_t stream) {
    const float* x = (const float*)d_in[0];
    const int* edge_index = (const int*)d_in[1];
    int n_edges = in_sizes[1] / 2;
    const int* src = edge_index;            // row 0: source j
    const int* dst = edge_index + n_edges;  // row 1: target i
    float* out = (float*)d_out;
    int n_nodes = out_size / D_FEAT;

    int nb = (n_nodes + BKT_NODES - 1) >> BKT_SHIFT;     // 782

    // ---- preferred: XCD-sharded dense bin, 4-dispatch path ----
    {
        // layout: bin[nb<<BKTSH] | cursors[NREP*nb] | ovfn[1] | ovfb[2*OVFTOT]
        size_t w_bin = (size_t)nb << BKTSH;              // 25.6MB @ nb=782
        size_t w_cur = (size_t)NREP * nb;
        size_t need = (w_bin + w_cur + 1 + 2 * (size_t)OVFTOT) * sizeof(u32);
        if (n_nodes <= (1 << 17) && need <= ws_size) {
            u32* bin     = (u32*)d_ws;
            u32* cursors = bin + w_bin;
            u32* ovfn    = cursors + w_cur;
            u32* ovfb    = ovfn + 1;
            int zero_words = (int)(w_cur + 1);           // cursors + ovfn
            k_zero8<<<(zero_words + 511) / 512, 512, 0, stream>>>(cursors, zero_words);
            k_scatter9<<<(n_edges + 511) / 512, 512, 0, stream>>>(src, dst, cursors, bin,
                                                                  ovfb, ovfn, n_edges, nb);
            k_gather9<<<nb, 512, 0, stream>>>(x, cursors, bin, out, n_nodes, nb);
            k_ovf<<<(OVFTOT * 8 + 255) / 256, 256, 0, stream>>>(x, ovfb, ovfn, out, n_nodes);
            return;
        }
    }

    // ---- fallback: proven sparse 2-kernel path ----
    size_t sc_lds = ((size_t)nb * CAP + nb) * sizeof(u32);   // 53.2 KB @ nb=782
    if (n_nodes <= (1 << 17) && sc_lds <= 64 * 1024) {
        const int ncand[3] = {512, 384, 256};
        for (int ci = 0; ci < 3; ++ci) {
            int nsub = ncand[ci];
            int chunk = (n_edges + nsub - 1) / nsub;
            size_t need = (512
                           + 2 * (size_t)nsub * OVFB
                           + (((size_t)nb * nsub) << CAPSH))
                          * sizeof(u32);
            if (need > ws_size) continue;

            u32* ovfn = (u32*)d_ws;
            u32* ovfb = ovfn + 512;
            u32* bin  = ovfb + 2 * (size_t)nsub * OVFB;

            k_scatter6<<<nsub, 512, sc_lds, stream>>>(src, dst, bin, ovfb, ovfn,
                                                      n_edges, nb, nsub, chunk);
            k_gather7<<<nb, 512, 0, stream>>>(x, bin, ovfb, ovfn, out,
                                              n_nodes, nb, nsub);
            return;
        }
    }

    // last-resort: atomic path
    mp_zero_kernel<<<(out_size + 255) / 256, 256, 0, stream>>>(out, out_size);
    int total_thr = n_edges * 8;
    mp_scatter_kernel<<<(total_thr + 255) / 256, 256, 0, stream>>>(x, src, dst, out, n_edges);
}